// Round 7
// baseline (1655.057 us; speedup 1.0000x reference)
//
#include <hip/hip_runtime.h>

#define T_LEN 2048
#define HID 64
#define NG 256     // 4*HID gate rows per layer
#define EMB 128
#define NITER (T_LEN + 4)

typedef _Float16 half2_t __attribute__((ext_vector_type(2)));
typedef unsigned uint4v __attribute__((ext_vector_type(4)));

#if __has_builtin(__builtin_amdgcn_exp2f)
#define EXP2F(x) __builtin_amdgcn_exp2f(x)
#else
#define EXP2F(x) exp2f(x)
#endif
#if __has_builtin(__builtin_amdgcn_rcpf)
#define RCPF(x) __builtin_amdgcn_rcpf(x)
#else
#define RCPF(x) (1.0f / (x))
#endif

#define LOG2E 1.4426950408889634f

// v_dot2_f32_f16: 2-way f16 dot, f32 accumulate.
__device__ __forceinline__ float fdot2(unsigned a, unsigned b, float c) {
    return __builtin_amdgcn_fdot2(__builtin_bit_cast(half2_t, a),
                                  __builtin_bit_cast(half2_t, b), c, false);
}

// DPP quad_perm move (VALU pipe; never the LDS pipe — R4 lesson).
template <int CTRL>
__device__ __forceinline__ float qmov(float v) {
    int r = __builtin_amdgcn_update_dpp(0, __builtin_bit_cast(int, v),
                                        CTRL, 0xF, 0xF, true);
    return __builtin_bit_cast(float, r);
}

// Butterfly allreduce across the quad (q = lane&3): 2 DPP+add steps.
__device__ __forceinline__ float qsum(float v) {
    v += qmov<0x4E>(v);   // quad_perm [2,3,0,1] : partner q^2
    v += qmov<0xB1>(v);   // quad_perm [1,0,3,2] : partner q^1
    return v;
}

// 16-MAC chunk dot: 8 packed-f16 weight pairs vs 8 h pairs, f32 accum.
__device__ __forceinline__ float dot16(uint4v wa, uint4v wb, uint4v ha, uint4v hb) {
    float a = fdot2(wa[0], ha[0], 0.f);
    a = fdot2(wa[1], ha[1], a);
    a = fdot2(wa[2], ha[2], a);
    a = fdot2(wa[3], ha[3], a);
    a = fdot2(wb[0], hb[0], a);
    a = fdot2(wb[1], hb[1], a);
    a = fdot2(wb[2], hb[2], a);
    a = fdot2(wb[3], hb[3], a);
    return a;
}

// Select item q of (a0..a3) — 3 v_cndmask.
__device__ __forceinline__ float sel4(float a0, float a1, float a2, float a3, int q) {
    float lo = (q & 1) ? a1 : a0;
    float hi = (q & 1) ? a3 : a2;
    return (q & 2) ? hi : lo;
}

// Load 16 floats of row `row`, cols [16q,16q+16), scale, pack to 8 half2.
__device__ __forceinline__ void cvt_chunk(const float* __restrict__ W, int row, int q,
                                          float s, uint4v& a, uint4v& b) {
    const float4* p = reinterpret_cast<const float4*>(W + row * HID + q * 16);
    float4 v0 = p[0], v1 = p[1], v2 = p[2], v3 = p[3];
    half2_t h0{(_Float16)(v0.x * s), (_Float16)(v0.y * s)};
    half2_t h1{(_Float16)(v0.z * s), (_Float16)(v0.w * s)};
    half2_t h2{(_Float16)(v1.x * s), (_Float16)(v1.y * s)};
    half2_t h3{(_Float16)(v1.z * s), (_Float16)(v1.w * s)};
    half2_t h4{(_Float16)(v2.x * s), (_Float16)(v2.y * s)};
    half2_t h5{(_Float16)(v2.z * s), (_Float16)(v2.w * s)};
    half2_t h6{(_Float16)(v3.x * s), (_Float16)(v3.y * s)};
    half2_t h7{(_Float16)(v3.z * s), (_Float16)(v3.w * s)};
    a[0] = __builtin_bit_cast(unsigned, h0); a[1] = __builtin_bit_cast(unsigned, h1);
    a[2] = __builtin_bit_cast(unsigned, h2); a[3] = __builtin_bit_cast(unsigned, h3);
    b[0] = __builtin_bit_cast(unsigned, h4); b[1] = __builtin_bit_cast(unsigned, h5);
    b[2] = __builtin_bit_cast(unsigned, h6); b[3] = __builtin_bit_cast(unsigned, h7);
}

// One block per batch; 768 threads = 3 stages x 4 waves.
// CHUNKED-DOT layout: lane = hloc*4 + q. Lane reads only h-chunk q (16 f16 ->
// 2 ds_read_b128/wave, 4 broadcast groups) and computes 4 per-class chunk
// partials; full sums via DPP quad butterfly (VALU pipe). Cuts per-CU LDS
// h-traffic 4x (96 -> 24 b128/iter), the co-dominant pipe per R6 analysis.
// Lane q then owns gate class q of its hidx (per-lane act constants), qbcast
// re-gathers i/f/g/o, quad-redundant cell update (R5-proven).
// 5-task schedule (R3..R6, numerics-verified): S0: h0[s] + p1[s-1];
// S1: h1[s-2] + p2[s-3]; S2: h2[s-4]. ONE barrier/iter; loop is global-free.
// Empty asm "+v" pins force the 16 weight quads into ARCH VGPRs (kills the
// v_accvgpr_read-per-fdot2 tax diagnosed from VGPR_Count=76 in R3-R6).
__global__ __launch_bounds__(768, 3) void lstm3_fused(
    const float* __restrict__ x,
    const float* __restrict__ Wih0, const float* __restrict__ Whh0,
    const float* __restrict__ bih0, const float* __restrict__ bhh0,
    const float* __restrict__ Wih1, const float* __restrict__ Whh1,
    const float* __restrict__ bih1, const float* __restrict__ bhh1,
    const float* __restrict__ Wih2, const float* __restrict__ Whh2,
    const float* __restrict__ bih2, const float* __restrict__ bhh2,
    const float* __restrict__ fcW,  const float* __restrict__ fcb,
    float* __restrict__ out)
{
    const int b     = blockIdx.x;
    const int tid   = threadIdx.x;
    const int stage = tid >> 8;        // 0,1,2 (wave-uniform)
    const int lane  = tid & 63;
    const int wv    = (tid >> 6) & 3;  // wave within stage
    const int hloc  = lane >> 2;       // 0..15
    const int q     = lane & 3;        // quad index = chunk = owned gate class
    const int hidx  = wv * 16 + hloc;  // h index [0,64)
    const int qrow  = q * HID + hidx;  // this lane's OWNED gate row
    const int pidx  = wv * 64 + lane;  // p slot = lane-linear (conflict-free)

    __shared__ __align__(16) _Float16 h0f[2][HID];
    __shared__ __align__(16) _Float16 h1f[2][HID];
    __shared__ __align__(16) _Float16 h2f[2][HID];
    __shared__ float p1buf[2][NG], p2buf[2][NG];
    __shared__ __align__(16) float xs[NITER];     // zero-padded tail

    {
        const float4* xg4 = reinterpret_cast<const float4*>(x + b * T_LEN);
        float4* xs4 = reinterpret_cast<float4*>(xs);
        if (tid < T_LEN / 4) xs4[tid] = xg4[tid];
        if (tid == 767) xs4[T_LEN / 4] = make_float4(0.f, 0.f, 0.f, 0.f);
    }
    if (tid < HID) {
        h0f[0][tid] = (_Float16)0.f; h0f[1][tid] = (_Float16)0.f;
        h1f[0][tid] = (_Float16)0.f; h1f[1][tid] = (_Float16)0.f;
        h2f[0][tid] = (_Float16)0.f; h2f[1][tid] = (_Float16)0.f;
    }

    // Per-class exp2-space scales (class 2 = tanh).
    const float s0c = -LOG2E, s1c = -LOG2E, s2c = -2.f * LOG2E, s3c = -LOG2E;
    // This lane's act constants (for its owned class q).
    const bool  isg = (q == 2);
    const float sEq = isg ? (-2.f * LOG2E) : (-LOG2E);
    const float sA  = isg ?  2.f :  1.f;
    const float sB  = isg ? -1.f :  0.f;

    // Weight chunks: wh = own-layer recurrent, wi = next-layer ih (p-task).
    // 4 classes x 2 uint4v each = 16 quads = 64 VGPRs total.
    uint4v w0a, w0b, w1a, w1b, w2a, w2b, w3a, w3b;   // wh
    uint4v i0a, i0b, i1a, i1b, i2a, i2b, i3a, i3b;   // wi
    float wx0 = 0.f, bj = 0.f;
    {
        const float* Wh = (stage == 0) ? Whh0 : (stage == 1) ? Whh1 : Whh2;
        const float* Wi = (stage == 0) ? Wih1 : (stage == 1) ? Wih2 : Whh2; // S2 wi unused
        const float* bi = (stage == 0) ? bih0 : (stage == 1) ? bih1 : bih2;
        const float* bh = (stage == 0) ? bhh0 : (stage == 1) ? bhh1 : bhh2;
        cvt_chunk(Wh, 0 * HID + hidx, q, s0c, w0a, w0b);
        cvt_chunk(Wh, 1 * HID + hidx, q, s1c, w1a, w1b);
        cvt_chunk(Wh, 2 * HID + hidx, q, s2c, w2a, w2b);
        cvt_chunk(Wh, 3 * HID + hidx, q, s3c, w3a, w3b);
        if (stage < 2) {
            cvt_chunk(Wi, 0 * HID + hidx, q, s0c, i0a, i0b);
            cvt_chunk(Wi, 1 * HID + hidx, q, s1c, i1a, i1b);
            cvt_chunk(Wi, 2 * HID + hidx, q, s2c, i2a, i2b);
            cvt_chunk(Wi, 3 * HID + hidx, q, s3c, i3a, i3b);
        } else {
            i0a = i0b = i1a = i1b = i2a = i2b = i3a = i3b = uint4v{0, 0, 0, 0};
        }
        bj = (bi[qrow] + bh[qrow]) * sEq;
        if (stage == 0) wx0 = Wih0[qrow] * sEq;   // Wih0 is [256,1]
    }

    // Hoisted LDS pointers. Lane reads chunk q of its stage's ring.
    _Float16* ring = (stage == 0) ? h0f[0] : (stage == 1) ? h1f[0] : h2f[0];
    const uint4v* Rd0 = reinterpret_cast<const uint4v*>(ring + q * 16);
    const uint4v* Rd1 = reinterpret_cast<const uint4v*>(ring + HID + q * 16);
    _Float16* Aw = ring + hidx;                   // + wr*HID at use
    const float* Pin  = (stage == 1) ? &p1buf[0][pidx] : &p2buf[0][pidx];
    float*       Pout = (stage == 0) ? &p1buf[0][pidx] : &p2buf[0][pidx];
    const int soff = 2 * stage;

    float c = 0.f;                     // cell state (4 consistent quad copies)
    __syncthreads();

    for (int s = 0; s < NITER; ++s) {
        const int rd = (s + 1) & 1;
        const int wr = s & 1;

        // Pin weights to arch VGPRs (empty asm: 0 instructions, RA-only).
        asm volatile("" : "+v"(w0a), "+v"(w0b), "+v"(w1a), "+v"(w1b),
                          "+v"(w2a), "+v"(w2b), "+v"(w3a), "+v"(w3b));
        asm volatile("" : "+v"(i0a), "+v"(i0b), "+v"(i1a), "+v"(i1b),
                          "+v"(i2a), "+v"(i2b), "+v"(i3a), "+v"(i3b));

        // Own h-chunk: 2x ds_read_b128, 4 broadcast groups (conflict-free).
        const uint4v* hp = rd ? Rd1 : Rd0;
        uint4v ha = hp[0], hb = hp[1];

        // 4 per-class chunk partials + quad butterfly -> full 64-dots.
        float d0 = qsum(dot16(w0a, w0b, ha, hb));
        float d1 = qsum(dot16(w1a, w1b, ha, hb));
        float d2 = qsum(dot16(w2a, w2b, ha, hb));
        float d3 = qsum(dot16(w3a, w3b, ha, hb));
        float dsel = sel4(d0, d1, d2, d3, q);      // this lane's class

        float acc;
        if (stage == 0) {
            acc = dsel + fmaf(wx0, xs[s], bj);
        } else {
            acc = dsel + (bj + (rd ? Pin[NG] : Pin[0]));   // p[rd][pidx]
        }

        // p-task (S0,S1): next layer's ih-dot on the same h chunk.
        if (stage < 2) {
            float p0 = qsum(dot16(i0a, i0b, ha, hb));
            float p1 = qsum(dot16(i1a, i1b, ha, hb));
            float p2 = qsum(dot16(i2a, i2b, ha, hb));
            float p3 = qsum(dot16(i3a, i3b, ha, hb));
            (wr ? Pout[NG] : Pout[0]) = sel4(p0, p1, p2, p3, q);
        }

        // Own gate activation (exp2-space prescaled; raw v_exp/v_rcp).
        float a = fmaf(sA, RCPF(1.f + EXP2F(acc)), sB);

        // Re-gather i,f,g,o across the quad (VALU-pipe DPP).
        float gi = qmov<0x00>(a);
        float gf = qmov<0x55>(a);
        float gg = qmov<0xAA>(a);
        float go = qmov<0xFF>(a);

        if ((unsigned)(s - soff) < (unsigned)T_LEN) {
            c = fmaf(gf, c, gi * gg);
            float tc = fmaf(2.f, RCPF(1.f + EXP2F(-2.f * LOG2E * c)), -1.f);
            float h  = go * tc;
            if (q == 0) Aw[wr ? HID : 0] = (_Float16)h;
        }
        __syncthreads();   // ring + p-buffer writes visible for iter s+1
    }

    // Final FC (f32). Last S2 write: s=2051 (odd) -> slot 1 => h2f[1].
    if (tid < EMB) {
        float acc = fcb[tid];
        const _Float16* hf = h2f[1];
        const float4* W4 = reinterpret_cast<const float4*>(fcW + tid * HID);
        #pragma unroll
        for (int k = 0; k < 16; ++k) {
            float4 wv4 = W4[k];
            acc = fmaf(wv4.x, (float)hf[4 * k + 0], acc);
            acc = fmaf(wv4.y, (float)hf[4 * k + 1], acc);
            acc = fmaf(wv4.z, (float)hf[4 * k + 2], acc);
            acc = fmaf(wv4.w, (float)hf[4 * k + 3], acc);
        }
        out[b * EMB + tid] = acc;
    }
}

extern "C" void kernel_launch(void* const* d_in, const int* in_sizes, int n_in,
                              void* d_out, int out_size, void* d_ws, size_t ws_size,
                              hipStream_t stream) {
    const float* x    = (const float*)d_in[0];
    const float* Wih0 = (const float*)d_in[1];
    const float* Whh0 = (const float*)d_in[2];
    const float* bih0 = (const float*)d_in[3];
    const float* bhh0 = (const float*)d_in[4];
    const float* Wih1 = (const float*)d_in[5];
    const float* Whh1 = (const float*)d_in[6];
    const float* bih1 = (const float*)d_in[7];
    const float* bhh1 = (const float*)d_in[8];
    const float* Wih2 = (const float*)d_in[9];
    const float* Whh2 = (const float*)d_in[10];
    const float* bih2 = (const float*)d_in[11];
    const float* bhh2 = (const float*)d_in[12];
    const float* fcW  = (const float*)d_in[13];
    const float* fcb  = (const float*)d_in[14];
    float* out = (float*)d_out;

    lstm3_fused<<<dim3(256), dim3(768), 0, stream>>>(
        x, Wih0, Whh0, bih0, bhh0,
        Wih1, Whh1, bih1, bhh1,
        Wih2, Whh2, bih2, bhh2,
        fcW, fcb, out);
}

// Round 8
// 1480.638 us; speedup vs baseline: 1.1178x; 1.1178x over previous
//
#include <hip/hip_runtime.h>

#define T_LEN 2048
#define HID 64
#define NG 256     // 4*HID gate rows per layer
#define EMB 128
#define NITER (T_LEN + 4)

typedef _Float16 half2_t __attribute__((ext_vector_type(2)));

#if __has_builtin(__builtin_amdgcn_exp2f)
#define EXP2F(x) __builtin_amdgcn_exp2f(x)
#else
#define EXP2F(x) exp2f(x)
#endif
#if __has_builtin(__builtin_amdgcn_rcpf)
#define RCPF(x) __builtin_amdgcn_rcpf(x)
#else
#define RCPF(x) (1.0f / (x))
#endif

#define LOG2E 1.4426950408889634f

// v_dot2_f32_f16: 2-way f16 dot, f32 accumulate.
__device__ __forceinline__ float fdot2(uint32_t a, uint32_t b, float c) {
    return __builtin_amdgcn_fdot2(__builtin_bit_cast(half2_t, a),
                                  __builtin_bit_cast(half2_t, b), c, false);
}

// Quad broadcast via DPP quad_perm (VALU pipe; R4 showed __shfl = LDS pipe = slow).
template <int CTRL>
__device__ __forceinline__ float qbcast(float v) {
    int r = __builtin_amdgcn_update_dpp(0, __builtin_bit_cast(int, v),
                                        CTRL, 0xF, 0xF, true);
    return __builtin_bit_cast(float, r);
}

// Load 64 f16 (128 B) from LDS as 8x uint4 (ds_read_b128, same-addr broadcast).
__device__ __forceinline__ void load_h(const _Float16* hbase, uint32_t* u) {
    const uint4* p = reinterpret_cast<const uint4*>(hbase);
    #pragma unroll
    for (int k = 0; k < 8; ++k) {
        uint4 v = p[k];
        u[4 * k + 0] = v.x; u[4 * k + 1] = v.y;
        u[4 * k + 2] = v.z; u[4 * k + 3] = v.w;
    }
}

// 64-MAC dot, 4 partial accumulators (short serial chains).
__device__ __forceinline__ float dot64(const uint32_t* w, const uint32_t* h) {
    float a0 = 0.f, a1 = 0.f, a2 = 0.f, a3 = 0.f;
    #pragma unroll
    for (int k = 0; k < 32; k += 4) {
        a0 = fdot2(w[k + 0], h[k + 0], a0);
        a1 = fdot2(w[k + 1], h[k + 1], a1);
        a2 = fdot2(w[k + 2], h[k + 2], a2);
        a3 = fdot2(w[k + 3], h[k + 3], a3);
    }
    return (a0 + a1) + (a2 + a3);
}

// One 64-float weight row -> 32 packed f16 pairs in VGPRs.
__device__ __forceinline__ void cvt_row(const float* __restrict__ W, int row, uint32_t* dst) {
    const float4* W4 = reinterpret_cast<const float4*>(W + row * HID);
    #pragma unroll
    for (int k = 0; k < 16; ++k) {
        float4 v = W4[k];
        half2_t a{(_Float16)v.x, (_Float16)v.y};
        half2_t b{(_Float16)v.z, (_Float16)v.w};
        dst[2 * k]     = __builtin_bit_cast(uint32_t, a);
        dst[2 * k + 1] = __builtin_bit_cast(uint32_t, b);
    }
}

// One block per batch element; 768 threads = 3 stages x 4 waves (R5 structure,
// the session best). Lane map: lane = hloc*4 + cls; quad holds the 4 gate
// classes of one h-index -> DPP quad_perm exchange; ONE barrier/iter.
// 5-task wavefront pipeline: S0: h0[s] + p1[s-1]; S1: h1[s-2] + p2[s-3];
// S2: h2[s-4]. p-buffers lane-linear (2-way = free). x staged in LDS.
//
// ROUND-8 CHANGE: amdgpu_waves_per_eu(3,3) — min=MAX=3. R2-R7 showed the RA
// minimizing arch VGPRs (~60-84) by homing the 64 weight regs in AGPRs and
// paying a v_accvgpr_read per fdot2 (~64 extra VALU/wave/iter, ~40% of
// runtime). Pinning max waves/EU at 3 (= what a 12-wave block gives anyway)
// removes the RA's incentive: budget 168 arch VGPRs, weights stay architectural.
__global__ __launch_bounds__(768)
__attribute__((amdgpu_waves_per_eu(3, 3)))
void lstm3_fused(
    const float* __restrict__ x,
    const float* __restrict__ Wih0, const float* __restrict__ Whh0,
    const float* __restrict__ bih0, const float* __restrict__ bhh0,
    const float* __restrict__ Wih1, const float* __restrict__ Whh1,
    const float* __restrict__ bih1, const float* __restrict__ bhh1,
    const float* __restrict__ Wih2, const float* __restrict__ Whh2,
    const float* __restrict__ bih2, const float* __restrict__ bhh2,
    const float* __restrict__ fcW,  const float* __restrict__ fcb,
    float* __restrict__ out)
{
    const int b     = blockIdx.x;
    const int tid   = threadIdx.x;
    const int stage = tid >> 8;        // 0,1,2 (wave-uniform)
    const int lane  = tid & 63;
    const int wv    = (tid >> 6) & 3;  // wave within stage
    const int hloc  = lane >> 2;       // 0..15
    const int cls   = lane & 3;        // 0=i,1=f,2=g,3=o (quad-lane index)
    const int hidx  = wv * 16 + hloc;  // h index [0,64)
    const int row   = cls * HID + hidx;// gate row [0,256)
    const int pidx  = hidx * 4 + cls;  // p-buffer slot (lane-linear per wave)

    __shared__ __align__(16) _Float16 h0f[2][HID];
    __shared__ __align__(16) _Float16 h1f[2][HID];
    __shared__ __align__(16) _Float16 h2f[2][HID];
    __shared__ float p1buf[2][NG], p2buf[2][NG];
    __shared__ float hfin[HID];
    __shared__ __align__(16) float xs[T_LEN];

    // Stage x[b,0,:] into LDS (512 float4, coalesced, one pass).
    {
        const float4* xg4 = reinterpret_cast<const float4*>(x + b * T_LEN);
        float4* xs4 = reinterpret_cast<float4*>(xs);
        if (tid < T_LEN / 4) xs4[tid] = xg4[tid];
    }
    if (tid < HID) {
        h0f[0][tid] = (_Float16)0.f; h0f[1][tid] = (_Float16)0.f;
        h1f[0][tid] = (_Float16)0.f; h1f[1][tid] = (_Float16)0.f;
        h2f[0][tid] = (_Float16)0.f; h2f[1][tid] = (_Float16)0.f;
    }

    uint32_t wh[32], wi[32];           // 64 VGPRs of packed f16 weights
    float wx0 = 0.f, bj = 0.f;
    if (stage == 0) {
        wx0 = Wih0[row];               // Wih0 is [256,1]
        bj  = bih0[row] + bhh0[row];
        cvt_row(Whh0, row, wh);
        cvt_row(Wih1, row, wi);        // p1 task
    } else if (stage == 1) {
        bj = bih1[row] + bhh1[row];
        cvt_row(Whh1, row, wh);
        cvt_row(Wih2, row, wi);        // p2 task
    } else {
        bj = bih2[row] + bhh2[row];
        cvt_row(Whh2, row, wh);
        #pragma unroll
        for (int k = 0; k < 32; ++k) wi[k] = 0;
    }

    // Branchless activation: act(x) = sA * rcp(1 + exp2(sE*x)) + sB.
    // cls==2 (g-gate) -> tanh, else sigmoid. log2e folded into sE.
    const bool  isg = (cls == 2);
    const float sE  = isg ? (-2.f * LOG2E) : (-LOG2E);
    const float sA  = isg ?  2.f :  1.f;
    const float sB  = isg ? -1.f :  0.f;

    float c = 0.f;                     // cell state (4 consistent quad copies)
    __syncthreads();

    for (int s = 0; s < NITER; ++s) {
        const int rd = (s + 1) & 1;    // slot written at iter s-1
        const int wr = s & 1;

        bool act;
        float acc;
        uint32_t hv[32];
        if (stage == 0) {
            act = (s < T_LEN);
            load_h(h0f[rd], hv);                       // h0[s-1]
            acc = dot64(wh, hv) + fmaf(wx0, xs[act ? s : 0], bj);
            p1buf[wr][pidx] = dot64(wi, hv);           // p1[s-1] = Wih1.h0[s-1]
        } else if (stage == 1) {
            act = (s >= 2 && s <= T_LEN + 1);
            float p = p1buf[rd][pidx];                 // p1[s-2]
            load_h(h1f[rd], hv);                       // h1[s-3]
            acc = dot64(wh, hv) + (bj + p);
            p2buf[wr][pidx] = dot64(wi, hv);           // p2[s-3] = Wih2.h1[s-3]
        } else {
            act = (s >= 4);
            float p = p2buf[rd][pidx];                 // p2[s-4]
            load_h(h2f[rd], hv);                       // h2[s-5]
            acc = dot64(wh, hv) + (bj + p);
        }

        // Own gate activation (branchless; raw v_exp/v_rcp; sigmoid/tanh via
        // act = sA * rcp(1 + exp2(sE*acc)) + sB).
        float a = fmaf(sA, RCPF(1.f + EXP2F(sE * acc)), sB);

        // Quad gate exchange: gate class q sits at quad-lane q (VALU-pipe DPP).
        float gi = qbcast<0x00>(a);
        float gf = qbcast<0x55>(a);
        float gg = qbcast<0xAA>(a);
        float go = qbcast<0xFF>(a);

        if (act) {
            c = fmaf(gf, c, gi * gg);                  // all 4 quad copies agree
            float tc = fmaf(2.f, RCPF(1.f + EXP2F(-2.f * LOG2E * c)), -1.f);
            float h  = go * tc;
            if (cls == 0) {
                _Float16* ring = (stage == 0) ? h0f[wr]
                               : (stage == 1) ? h1f[wr] : h2f[wr];
                ring[hidx] = (_Float16)h;
                if (stage == 2 && s == NITER - 1) hfin[hidx] = h;  // h2[T-1]
            }
        }
        __syncthreads();   // ring + p-buffer writes visible for iter s+1
    }

    // Final FC (f32): out[b,m] = fcb[m] + fcW[m,:] . h2_last
    if (tid < EMB) {
        float acc = fcb[tid];
        const float4* W4 = reinterpret_cast<const float4*>(fcW + tid * HID);
        const float4* h4 = reinterpret_cast<const float4*>(hfin);
        #pragma unroll
        for (int k = 0; k < 16; ++k) {
            float4 wv4 = W4[k], hv4 = h4[k];
            acc = fmaf(wv4.x, hv4.x, acc);
            acc = fmaf(wv4.y, hv4.y, acc);
            acc = fmaf(wv4.z, hv4.z, acc);
            acc = fmaf(wv4.w, hv4.w, acc);
        }
        out[b * EMB + tid] = acc;
    }
}

extern "C" void kernel_launch(void* const* d_in, const int* in_sizes, int n_in,
                              void* d_out, int out_size, void* d_ws, size_t ws_size,
                              hipStream_t stream) {
    const float* x    = (const float*)d_in[0];
    const float* Wih0 = (const float*)d_in[1];
    const float* Whh0 = (const float*)d_in[2];
    const float* bih0 = (const float*)d_in[3];
    const float* bhh0 = (const float*)d_in[4];
    const float* Wih1 = (const float*)d_in[5];
    const float* Whh1 = (const float*)d_in[6];
    const float* bih1 = (const float*)d_in[7];
    const float* bhh1 = (const float*)d_in[8];
    const float* Wih2 = (const float*)d_in[9];
    const float* Whh2 = (const float*)d_in[10];
    const float* bih2 = (const float*)d_in[11];
    const float* bhh2 = (const float*)d_in[12];
    const float* fcW  = (const float*)d_in[13];
    const float* fcb  = (const float*)d_in[14];
    float* out = (float*)d_out;

    lstm3_fused<<<dim3(256), dim3(768), 0, stream>>>(
        x, Wih0, Whh0, bih0, bhh0,
        Wih1, Whh1, bih1, bhh1,
        Wih2, Whh2, bih2, bhh2,
        fcW, fcb, out);
}

// Round 9
// 1451.893 us; speedup vs baseline: 1.1399x; 1.0198x over previous
//
#include <hip/hip_runtime.h>

#define T_LEN 2048
#define HID 64
#define NG 256     // 4*HID gate rows per layer
#define EMB 128
#define NITER (T_LEN + 4)

typedef _Float16 half2_t __attribute__((ext_vector_type(2)));
typedef unsigned uint4v __attribute__((ext_vector_type(4)));

#if __has_builtin(__builtin_amdgcn_exp2f)
#define EXP2F(x) __builtin_amdgcn_exp2f(x)
#else
#define EXP2F(x) exp2f(x)
#endif
#if __has_builtin(__builtin_amdgcn_rcpf)
#define RCPF(x) __builtin_amdgcn_rcpf(x)
#else
#define RCPF(x) (1.0f / (x))
#endif

#define LOG2E 1.4426950408889634f

// v_dot2_f32_f16: 2-way f16 dot, f32 accumulate.
__device__ __forceinline__ float fdot2(unsigned a, unsigned b, float c) {
    return __builtin_amdgcn_fdot2(__builtin_bit_cast(half2_t, a),
                                  __builtin_bit_cast(half2_t, b), c, false);
}

// Quad broadcast via DPP quad_perm (VALU pipe; R4 showed __shfl = LDS pipe = slow).
template <int CTRL>
__device__ __forceinline__ float qbcast(float v) {
    int r = __builtin_amdgcn_update_dpp(0, __builtin_bit_cast(int, v),
                                        CTRL, 0xF, 0xF, true);
    return __builtin_bit_cast(float, r);
}

// 64-MAC dot on 8 uint4v quads (weights) vs 8 uint4v quads (h), no
// intermediate scalar arrays -> no v_mov repack (the R9 target).
// 4 partial accumulators.
__device__ __forceinline__ float dot64q(const uint4v* w, const uint4v* h, float a0) {
    float a1 = 0.f, a2 = 0.f, a3 = 0.f;
    #pragma unroll
    for (int k = 0; k < 8; ++k) {
        a0 = fdot2(w[k][0], h[k][0], a0);
        a1 = fdot2(w[k][1], h[k][1], a1);
        a2 = fdot2(w[k][2], h[k][2], a2);
        a3 = fdot2(w[k][3], h[k][3], a3);
    }
    return (a0 + a1) + (a2 + a3);
}

// One 64-float weight row -> 8 uint4v of packed f16 pairs, pre-scaled
// (exp2-space fold: sigmoid rows x -log2e, tanh(g) rows x -2log2e).
__device__ __forceinline__ void cvt_row(const float* __restrict__ W, int row,
                                        float s, uint4v* dst) {
    const float4* W4 = reinterpret_cast<const float4*>(W + row * HID);
    #pragma unroll
    for (int k = 0; k < 8; ++k) {
        float4 v0 = W4[2 * k], v1 = W4[2 * k + 1];
        half2_t p0{(_Float16)(v0.x * s), (_Float16)(v0.y * s)};
        half2_t p1{(_Float16)(v0.z * s), (_Float16)(v0.w * s)};
        half2_t p2{(_Float16)(v1.x * s), (_Float16)(v1.y * s)};
        half2_t p3{(_Float16)(v1.z * s), (_Float16)(v1.w * s)};
        uint4v q;
        q[0] = __builtin_bit_cast(unsigned, p0);
        q[1] = __builtin_bit_cast(unsigned, p1);
        q[2] = __builtin_bit_cast(unsigned, p2);
        q[3] = __builtin_bit_cast(unsigned, p3);
        dst[k] = q;
    }
}

// One block per batch element; 768 threads = 3 stages x 4 waves (R5 structure,
// the session best at 1474 us). Lane map: lane = hloc*4 + cls; the 4 gate
// classes of one h-index live in one quad -> DPP quad_perm exchange; ONE
// barrier per iteration. 5-task wavefront pipeline:
//   S0: gates0 -> h0[s];  p1[s-1] = Wih1 . h0[s-1]
//   S1: gates1 -> h1[s-2] (uses p1[s-2]);  p2[s-3] = Wih2 . h1[s-3]
//   S2: gates2 -> h2[s-4] (uses p2[s-4])
// p-buffers lane-linear (2-way bank aliasing = free). x staged in LDS,
// zero-padded to NITER (no boundary select). Loop body is global-free.
// R9 deltas vs R5: direct-uint4v dots (no hv[] scalarization movs),
// exp2-prescaled weights/bias (no per-iter sE mul), unconditional p-writes.
__global__ __launch_bounds__(768, 3) void lstm3_fused(
    const float* __restrict__ x,
    const float* __restrict__ Wih0, const float* __restrict__ Whh0,
    const float* __restrict__ bih0, const float* __restrict__ bhh0,
    const float* __restrict__ Wih1, const float* __restrict__ Whh1,
    const float* __restrict__ bih1, const float* __restrict__ bhh1,
    const float* __restrict__ Wih2, const float* __restrict__ Whh2,
    const float* __restrict__ bih2, const float* __restrict__ bhh2,
    const float* __restrict__ fcW,  const float* __restrict__ fcb,
    float* __restrict__ out)
{
    const int b     = blockIdx.x;
    const int tid   = threadIdx.x;
    const int stage = tid >> 8;        // 0,1,2 (wave-uniform)
    const int lane  = tid & 63;
    const int wv    = (tid >> 6) & 3;  // wave within stage
    const int hloc  = lane >> 2;       // 0..15
    const int cls   = lane & 3;        // 0=i,1=f,2=g,3=o (quad-lane index)
    const int hidx  = wv * 16 + hloc;  // h index [0,64)
    const int row   = cls * HID + hidx;// gate row [0,256)
    const int pidx  = hidx * 4 + cls;  // p slot = wv*64+lane (lane-linear)

    __shared__ __align__(16) _Float16 h0f[2][HID];
    __shared__ __align__(16) _Float16 h1f[2][HID];
    __shared__ __align__(16) _Float16 h2f[2][HID];
    __shared__ float p1buf[2][NG], p2buf[2][NG];
    __shared__ float hfin[HID];
    __shared__ __align__(16) float xs[NITER];     // zero-padded tail

    // Stage x[b,0,:] into LDS (512 float4, coalesced); zero the pad.
    {
        const float4* xg4 = reinterpret_cast<const float4*>(x + b * T_LEN);
        float4* xs4 = reinterpret_cast<float4*>(xs);
        if (tid < T_LEN / 4) xs4[tid] = xg4[tid];
        if (tid == T_LEN / 4) xs4[T_LEN / 4] = make_float4(0.f, 0.f, 0.f, 0.f);
    }
    if (tid < HID) {
        h0f[0][tid] = (_Float16)0.f; h0f[1][tid] = (_Float16)0.f;
        h1f[0][tid] = (_Float16)0.f; h1f[1][tid] = (_Float16)0.f;
        h2f[0][tid] = (_Float16)0.f; h2f[1][tid] = (_Float16)0.f;
    }

    // exp2-space scale for this lane's gate class (cls 2 = tanh).
    const bool  isg = (cls == 2);
    const float sE  = isg ? (-2.f * LOG2E) : (-LOG2E);
    const float sA  = isg ?  2.f :  1.f;
    const float sB  = isg ? -1.f :  0.f;

    uint4v wh[8] = {}, wi[8] = {};     // 64 VGPRs of prescaled packed f16
    float wx0 = 0.f, bj = 0.f;
    if (stage == 0) {
        wx0 = Wih0[row] * sE;          // Wih0 is [256,1]
        bj  = (bih0[row] + bhh0[row]) * sE;
        cvt_row(Whh0, row, sE, wh);
        cvt_row(Wih1, row, sE, wi);    // p1 task (consumer lane has same cls)
    } else if (stage == 1) {
        bj = (bih1[row] + bhh1[row]) * sE;
        cvt_row(Whh1, row, sE, wh);
        cvt_row(Wih2, row, sE, wi);    // p2 task
    } else {
        bj = (bih2[row] + bhh2[row]) * sE;
        cvt_row(Whh2, row, sE, wh);
    }

    float c = 0.f;                     // cell state (4 consistent quad copies)
    __syncthreads();

    for (int s = 0; s < NITER; ++s) {
        const int rd = (s + 1) & 1;    // slot written at iter s-1
        const int wr = s & 1;

        bool act;
        float acc;
        uint4v hv[8];
        if (stage == 0) {
            act = (s < T_LEN);
            const uint4v* hp = reinterpret_cast<const uint4v*>(h0f[rd]);
            #pragma unroll
            for (int k = 0; k < 8; ++k) hv[k] = hp[k];     // h0[s-1]
            acc = dot64q(wh, hv, fmaf(wx0, xs[s], bj));
            p1buf[wr][pidx] = dot64q(wi, hv, 0.f);         // p1[s-1]
        } else if (stage == 1) {
            act = (s >= 2 && s <= T_LEN + 1);
            float p = p1buf[rd][pidx];                     // p1[s-2]
            const uint4v* hp = reinterpret_cast<const uint4v*>(h1f[rd]);
            #pragma unroll
            for (int k = 0; k < 8; ++k) hv[k] = hp[k];     // h1[s-3]
            acc = dot64q(wh, hv, bj + p);
            p2buf[wr][pidx] = dot64q(wi, hv, 0.f);         // p2[s-3]
        } else {
            act = (s >= 4);
            float p = p2buf[rd][pidx];                     // p2[s-4]
            const uint4v* hp = reinterpret_cast<const uint4v*>(h2f[rd]);
            #pragma unroll
            for (int k = 0; k < 8; ++k) hv[k] = hp[k];     // h2[s-5]
            acc = dot64q(wh, hv, bj + p);
        }

        // Gate activation: already in exp2 space (weights prescaled).
        float a = fmaf(sA, RCPF(1.f + EXP2F(acc)), sB);

        // Quad gate exchange (VALU-pipe DPP).
        float gi = qbcast<0x00>(a);
        float gf = qbcast<0x55>(a);
        float gg = qbcast<0xAA>(a);
        float go = qbcast<0xFF>(a);

        if (act) {
            c = fmaf(gf, c, gi * gg);                      // 4 quad copies agree
            float tc = fmaf(2.f, RCPF(1.f + EXP2F(-2.f * LOG2E * c)), -1.f);
            float h  = go * tc;
            if (cls == 0) {
                _Float16* ring = (stage == 0) ? h0f[wr]
                               : (stage == 1) ? h1f[wr] : h2f[wr];
                ring[hidx] = (_Float16)h;
                if (stage == 2 && s == NITER - 1) hfin[hidx] = h;  // h2[T-1]
            }
        }
        __syncthreads();   // ring + p-buffer writes visible for iter s+1
    }

    // Final FC (f32): out[b,m] = fcb[m] + fcW[m,:] . h2_last
    if (tid < EMB) {
        float acc = fcb[tid];
        const float4* W4 = reinterpret_cast<const float4*>(fcW + tid * HID);
        const float4* h4 = reinterpret_cast<const float4*>(hfin);
        #pragma unroll
        for (int k = 0; k < 16; ++k) {
            float4 wv4 = W4[k], hv4 = h4[k];
            acc = fmaf(wv4.x, hv4.x, acc);
            acc = fmaf(wv4.y, hv4.y, acc);
            acc = fmaf(wv4.z, hv4.z, acc);
            acc = fmaf(wv4.w, hv4.w, acc);
        }
        out[b * EMB + tid] = acc;
    }
}

extern "C" void kernel_launch(void* const* d_in, const int* in_sizes, int n_in,
                              void* d_out, int out_size, void* d_ws, size_t ws_size,
                              hipStream_t stream) {
    const float* x    = (const float*)d_in[0];
    const float* Wih0 = (const float*)d_in[1];
    const float* Whh0 = (const float*)d_in[2];
    const float* bih0 = (const float*)d_in[3];
    const float* bhh0 = (const float*)d_in[4];
    const float* Wih1 = (const float*)d_in[5];
    const float* Whh1 = (const float*)d_in[6];
    const float* bih1 = (const float*)d_in[7];
    const float* bhh1 = (const float*)d_in[8];
    const float* Wih2 = (const float*)d_in[9];
    const float* Whh2 = (const float*)d_in[10];
    const float* bih2 = (const float*)d_in[11];
    const float* bhh2 = (const float*)d_in[12];
    const float* fcW  = (const float*)d_in[13];
    const float* fcb  = (const float*)d_in[14];
    float* out = (float*)d_out;

    lstm3_fused<<<dim3(256), dim3(768), 0, stream>>>(
        x, Wih0, Whh0, bih0, bhh0,
        Wih1, Whh1, bih1, bhh1,
        Wih2, Whh2, bih2, bhh2,
        fcW, fcb, out);
}

// Round 10
// 1390.785 us; speedup vs baseline: 1.1900x; 1.0439x over previous
//
#include <hip/hip_runtime.h>

#define T_LEN 2048
#define HID 64
#define EMB 128
#define NITER (T_LEN + 4)

typedef _Float16 half2_t __attribute__((ext_vector_type(2)));
typedef unsigned uint4v __attribute__((ext_vector_type(4)));

#if __has_builtin(__builtin_amdgcn_exp2f)
#define EXP2F(x) __builtin_amdgcn_exp2f(x)
#else
#define EXP2F(x) exp2f(x)
#endif
#if __has_builtin(__builtin_amdgcn_rcpf)
#define RCPF(x) __builtin_amdgcn_rcpf(x)
#else
#define RCPF(x) (1.0f / (x))
#endif

#define LOG2E 1.4426950408889634f

__device__ __forceinline__ float fdot2(unsigned a, unsigned b, float c) {
    return __builtin_amdgcn_fdot2(__builtin_bit_cast(half2_t, a),
                                  __builtin_bit_cast(half2_t, b), c, false);
}

// 64-MAC dot: one full row held in-lane (8 uint4v of packed f16) vs the
// gathered h vector (8 uint4v). Two partial chains (16-deep) + final add.
__device__ __forceinline__ float dot32(const uint4v* w, const uint4v* a, float init) {
    float e = init, o = 0.f;
    #pragma unroll
    for (int q = 0; q < 8; ++q) {
        e = fdot2(w[q][0], a[q][0], e);
        o = fdot2(w[q][1], a[q][1], o);
        e = fdot2(w[q][2], a[q][2], e);
        o = fdot2(w[q][3], a[q][3], o);
    }
    return e + o;
}

__device__ __forceinline__ void gather8(const uint4v* p, uint4v* a) {
    #pragma unroll
    for (int q = 0; q < 8; ++q) a[q] = p[q];
}

// One 64-float weight row -> 8 uint4v packed f16, pre-scaled (exp2-space
// fold: sigmoid rows x -log2e, tanh(g) rows x -2log2e). R6-validated numerics.
__device__ __forceinline__ void cvt_row(const float* __restrict__ W, int row,
                                        float s, uint4v* dst) {
    const float4* W4 = reinterpret_cast<const float4*>(W + row * HID);
    #pragma unroll
    for (int k = 0; k < 8; ++k) {
        float4 v0 = W4[2 * k], v1 = W4[2 * k + 1];
        half2_t p0{(_Float16)(v0.x * s), (_Float16)(v0.y * s)};
        half2_t p1{(_Float16)(v0.z * s), (_Float16)(v0.w * s)};
        half2_t p2{(_Float16)(v1.x * s), (_Float16)(v1.y * s)};
        half2_t p3{(_Float16)(v1.z * s), (_Float16)(v1.w * s)};
        uint4v q;
        q[0] = __builtin_bit_cast(unsigned, p0);
        q[1] = __builtin_bit_cast(unsigned, p1);
        q[2] = __builtin_bit_cast(unsigned, p2);
        q[3] = __builtin_bit_cast(unsigned, p3);
        dst[k] = q;
    }
}

// H-INDEX-OWNER structure (Round 10). One block = one batch = 256 threads =
// 4 waves, ~1 wave/SIMD. Lane L of each wave owns h-index L of "its" layer:
// it holds ALL FOUR gate-class rows in registers, so gates never leave the
// lane (no DPP exchange, no quad redundancy), and the cell state is a plain
// per-lane scalar. 5 rows x 32 fdot2 = 160 fdot2/lane/step, equal per wave:
//   W0: whh0 rows (cell0) + wih1_i row   | gathers h0 (self-written)
//   W1: whh1 rows (cell1) + wih2_i row   | gathers h1 (self)
//   W2: whh2 rows (cell2) + wih1_f row   | gathers h2 (self) + h0
//   W3: wih1_{g,o} + wih2_{f,g,o} rows   | gathers h0 + h1
// ih-partials flow via lane-linear p-buffers (1-step slack, one barrier/step).
// The self-recurrence (whh . own ring) is same-wave -> ordered by lgkmcnt,
// not the barrier. Weights: 160 VGPRs/lane; launch_bounds(256,1) gives the
// RA a ~512-reg budget -> no occupancy reason to park them in AGPRs (the
// R2-R9 v_accvgpr_read tax). Weights/h f16 (exp2-prescaled), accum f32.
__global__ __launch_bounds__(256, 1) void lstm3_fused(
    const float* __restrict__ x,
    const float* __restrict__ Wih0, const float* __restrict__ Whh0,
    const float* __restrict__ bih0, const float* __restrict__ bhh0,
    const float* __restrict__ Wih1, const float* __restrict__ Whh1,
    const float* __restrict__ bih1, const float* __restrict__ bhh1,
    const float* __restrict__ Wih2, const float* __restrict__ Whh2,
    const float* __restrict__ bih2, const float* __restrict__ bhh2,
    const float* __restrict__ fcW,  const float* __restrict__ fcb,
    float* __restrict__ out)
{
    const int b  = blockIdx.x;
    const int tid = threadIdx.x;
    const int wv = tid >> 6;          // 0..3 (wave-uniform)
    const int L  = tid & 63;          // owned h-index / row-lane

    __shared__ __align__(16) _Float16 h0f[2][HID];
    __shared__ __align__(16) _Float16 h1f[2][HID];
    __shared__ __align__(16) _Float16 h2f[2][HID];
    __shared__ float p1buf[2][4 * HID], p2buf[2][4 * HID];
    __shared__ __align__(16) float xs[NITER];   // 2052 = 513 float4

    // Stage x[b,0,:] (512 float4 by 256 threads) + zero pad + zero rings.
    {
        const float4* xg4 = reinterpret_cast<const float4*>(x + b * T_LEN);
        float4* xs4 = reinterpret_cast<float4*>(xs);
        xs4[tid]       = xg4[tid];
        xs4[tid + 256] = xg4[tid + 256];
        if (tid == 0) xs4[512] = make_float4(0.f, 0.f, 0.f, 0.f);
    }
    if (tid < HID) {
        h0f[0][tid] = (_Float16)0.f; h0f[1][tid] = (_Float16)0.f;
        h1f[0][tid] = (_Float16)0.f; h1f[1][tid] = (_Float16)0.f;
        h2f[0][tid] = (_Float16)0.f; h2f[1][tid] = (_Float16)0.f;
    }

    const float sI = -LOG2E, sF = -LOG2E, sG = -2.f * LOG2E, sO = -LOG2E;

    // Per-wave row assignment (5 rows/lane).
    const float* Wm[5]; int Wr[5]; float sc[5];
    if (wv == 0) {
        Wm[0] = Whh0; Wm[1] = Whh0; Wm[2] = Whh0; Wm[3] = Whh0; Wm[4] = Wih1;
        Wr[0] = L; Wr[1] = 64 + L; Wr[2] = 128 + L; Wr[3] = 192 + L; Wr[4] = L;
        sc[0] = sI; sc[1] = sF; sc[2] = sG; sc[3] = sO; sc[4] = sI;
    } else if (wv == 1) {
        Wm[0] = Whh1; Wm[1] = Whh1; Wm[2] = Whh1; Wm[3] = Whh1; Wm[4] = Wih2;
        Wr[0] = L; Wr[1] = 64 + L; Wr[2] = 128 + L; Wr[3] = 192 + L; Wr[4] = L;
        sc[0] = sI; sc[1] = sF; sc[2] = sG; sc[3] = sO; sc[4] = sI;
    } else if (wv == 2) {
        Wm[0] = Whh2; Wm[1] = Whh2; Wm[2] = Whh2; Wm[3] = Whh2; Wm[4] = Wih1;
        Wr[0] = L; Wr[1] = 64 + L; Wr[2] = 128 + L; Wr[3] = 192 + L; Wr[4] = 64 + L;
        sc[0] = sI; sc[1] = sF; sc[2] = sG; sc[3] = sO; sc[4] = sF;
    } else {
        Wm[0] = Wih1; Wm[1] = Wih1; Wm[2] = Wih2; Wm[3] = Wih2; Wm[4] = Wih2;
        Wr[0] = 128 + L; Wr[1] = 192 + L; Wr[2] = 64 + L; Wr[3] = 128 + L; Wr[4] = 192 + L;
        sc[0] = sG; sc[1] = sO; sc[2] = sF; sc[3] = sG; sc[4] = sO;
    }

    uint4v w[5][8];
    #pragma unroll
    for (int k = 0; k < 5; ++k) cvt_row(Wm[k], Wr[k], sc[k], w[k]);

    // Cell-wave constants: 4 prescaled biases (+ Wih0 column for W0).
    float bias[4] = {0.f, 0.f, 0.f, 0.f};
    float wx[4]   = {0.f, 0.f, 0.f, 0.f};
    if (wv < 3) {
        const float* bi = (wv == 0) ? bih0 : (wv == 1) ? bih1 : bih2;
        const float* bh = (wv == 0) ? bhh0 : (wv == 1) ? bhh1 : bhh2;
        const float scl[4] = {sI, sF, sG, sO};
        #pragma unroll
        for (int k = 0; k < 4; ++k)
            bias[k] = (bi[k * 64 + L] + bh[k * 64 + L]) * scl[k];
        if (wv == 0) {
            #pragma unroll
            for (int k = 0; k < 4; ++k) wx[k] = Wih0[k * 64 + L] * scl[k];
        }
    }

    // Ring bases.
    _Float16* selfRing = (wv == 0) ? h0f[0] : (wv == 1) ? h1f[0] : h2f[0]; // wv3 unused-ish
    const float* pin   = (wv == 1) ? p1buf[0] : p2buf[0];                  // cell1/2 input

    float c = 0.f;
    __syncthreads();

    for (int s = 0; s < NITER; ++s) {
        const int rd = (s + 1) & 1;
        const int wr = s & 1;

        if (wv == 3) {
            // Pure producer wave: wih1_{g,o} vs h0, wih2_{f,g,o} vs h1.
            uint4v A[8];
            gather8(reinterpret_cast<const uint4v*>(h0f[rd]), A);
            p1buf[wr][128 + L] = dot32(w[0], A, 0.f);
            p1buf[wr][192 + L] = dot32(w[1], A, 0.f);
            uint4v B[8];
            gather8(reinterpret_cast<const uint4v*>(h1f[rd]), B);
            p2buf[wr][64 + L]  = dot32(w[2], B, 0.f);
            p2buf[wr][128 + L] = dot32(w[3], B, 0.f);
            p2buf[wr][192 + L] = dot32(w[4], B, 0.f);
        } else {
            uint4v A[8];
            gather8(reinterpret_cast<const uint4v*>(selfRing + rd * HID), A);

            // Accumulator inits: x-term (layer0) or p-buffer parts.
            float d0, d1, d2, d3;
            if (wv == 0) {
                float xv = xs[s];
                d0 = fmaf(wx[0], xv, bias[0]); d1 = fmaf(wx[1], xv, bias[1]);
                d2 = fmaf(wx[2], xv, bias[2]); d3 = fmaf(wx[3], xv, bias[3]);
            } else {
                const float* pb = pin + rd * 4 * HID;
                d0 = bias[0] + pb[L];       d1 = bias[1] + pb[64 + L];
                d2 = bias[2] + pb[128 + L]; d3 = bias[3] + pb[192 + L];
            }

            d0 = dot32(w[0], A, d0);
            d1 = dot32(w[1], A, d1);
            d2 = dot32(w[2], A, d2);
            d3 = dot32(w[3], A, d3);

            // Extra ih row for the next layer.
            if (wv == 2) {
                uint4v B[8];
                gather8(reinterpret_cast<const uint4v*>(h0f[rd]), B);
                p1buf[wr][64 + L] = dot32(w[4], B, 0.f);
            } else if (wv == 0) {
                p1buf[wr][L] = dot32(w[4], A, 0.f);
            } else {
                p2buf[wr][L] = dot32(w[4], A, 0.f);
            }

            // Gates: all four in-lane (exp2-space pre-activations).
            float ai = RCPF(1.f + EXP2F(d0));
            float af = RCPF(1.f + EXP2F(d1));
            float ag = fmaf(2.f, RCPF(1.f + EXP2F(d2)), -1.f);
            float ao = RCPF(1.f + EXP2F(d3));

            if ((unsigned)(s - 2 * wv) < (unsigned)T_LEN) {
                c = fmaf(af, c, ai * ag);
                float tc = fmaf(2.f, RCPF(1.f + EXP2F(-2.f * LOG2E * c)), -1.f);
                float h  = ao * tc;
                selfRing[wr * HID + L] = (_Float16)h;
            }
        }
        __syncthreads();   // cross-wave edges (p-bufs, cross-layer h): 1-step slack
    }

    // Final FC (f32): h2[T-1] written at s=2051 -> slot 1.
    if (tid < EMB) {
        float acc = fcb[tid];
        const _Float16* hf = h2f[1];
        const float4* W4 = reinterpret_cast<const float4*>(fcW + tid * HID);
        #pragma unroll
        for (int k = 0; k < 16; ++k) {
            float4 wv4 = W4[k];
            acc = fmaf(wv4.x, (float)hf[4 * k + 0], acc);
            acc = fmaf(wv4.y, (float)hf[4 * k + 1], acc);
            acc = fmaf(wv4.z, (float)hf[4 * k + 2], acc);
            acc = fmaf(wv4.w, (float)hf[4 * k + 3], acc);
        }
        out[b * EMB + tid] = acc;
    }
}

extern "C" void kernel_launch(void* const* d_in, const int* in_sizes, int n_in,
                              void* d_out, int out_size, void* d_ws, size_t ws_size,
                              hipStream_t stream) {
    const float* x    = (const float*)d_in[0];
    const float* Wih0 = (const float*)d_in[1];
    const float* Whh0 = (const float*)d_in[2];
    const float* bih0 = (const float*)d_in[3];
    const float* bhh0 = (const float*)d_in[4];
    const float* Wih1 = (const float*)d_in[5];
    const float* Whh1 = (const float*)d_in[6];
    const float* bih1 = (const float*)d_in[7];
    const float* bhh1 = (const float*)d_in[8];
    const float* Wih2 = (const float*)d_in[9];
    const float* Whh2 = (const float*)d_in[10];
    const float* bih2 = (const float*)d_in[11];
    const float* bhh2 = (const float*)d_in[12];
    const float* fcW  = (const float*)d_in[13];
    const float* fcb  = (const float*)d_in[14];
    float* out = (float*)d_out;

    lstm3_fused<<<dim3(256), dim3(256), 0, stream>>>(
        x, Wih0, Whh0, bih0, bhh0,
        Wih1, Whh1, bih1, bhh1,
        Wih2, Whh2, bih2, bhh2,
        fcW, fcb, out);
}

// Round 11
// 1212.498 us; speedup vs baseline: 1.3650x; 1.1470x over previous
//
#include <hip/hip_runtime.h>

#define T_LEN 2048
#define HID 64
#define EMB 128
#define NITER (T_LEN + 4)

typedef _Float16 half2_t __attribute__((ext_vector_type(2)));
typedef unsigned uint4v __attribute__((ext_vector_type(4)));

#if __has_builtin(__builtin_amdgcn_exp2f)
#define EXP2F(x) __builtin_amdgcn_exp2f(x)
#else
#define EXP2F(x) exp2f(x)
#endif
#if __has_builtin(__builtin_amdgcn_rcpf)
#define RCPF(x) __builtin_amdgcn_rcpf(x)
#else
#define RCPF(x) (1.0f / (x))
#endif

#define LOG2E 1.4426950408889634f

__device__ __forceinline__ float fdot2(unsigned a, unsigned b, float c) {
    return __builtin_amdgcn_fdot2(__builtin_bit_cast(half2_t, a),
                                  __builtin_bit_cast(half2_t, b), c, false);
}

// 64-MAC dot: full row in-lane (8 uint4v packed f16) vs gathered h.
__device__ __forceinline__ float dot32(const uint4v* w, const uint4v* a, float init) {
    float e = init, o = 0.f;
    #pragma unroll
    for (int q = 0; q < 8; ++q) {
        e = fdot2(w[q][0], a[q][0], e);
        o = fdot2(w[q][1], a[q][1], o);
        e = fdot2(w[q][2], a[q][2], e);
        o = fdot2(w[q][3], a[q][3], o);
    }
    return e + o;
}

__device__ __forceinline__ void gather8(const uint4v* p, uint4v* a) {
    #pragma unroll
    for (int q = 0; q < 8; ++q) a[q] = p[q];
}

// One 64-float weight row -> 8 uint4v packed f16, pre-scaled (exp2-space
// fold: sigmoid rows x -log2e, tanh(g) rows x -2log2e).
__device__ __forceinline__ void cvt_row(const float* __restrict__ W, int row,
                                        float s, uint4v* dst) {
    const float4* W4 = reinterpret_cast<const float4*>(W + row * HID);
    #pragma unroll
    for (int k = 0; k < 8; ++k) {
        float4 v0 = W4[2 * k], v1 = W4[2 * k + 1];
        half2_t p0{(_Float16)(v0.x * s), (_Float16)(v0.y * s)};
        half2_t p1{(_Float16)(v0.z * s), (_Float16)(v0.w * s)};
        half2_t p2{(_Float16)(v1.x * s), (_Float16)(v1.y * s)};
        half2_t p3{(_Float16)(v1.z * s), (_Float16)(v1.w * s)};
        uint4v q;
        q[0] = __builtin_bit_cast(unsigned, p0);
        q[1] = __builtin_bit_cast(unsigned, p1);
        q[2] = __builtin_bit_cast(unsigned, p2);
        q[3] = __builtin_bit_cast(unsigned, p3);
        dst[k] = q;
    }
}

// ROUND 11: R10's h-index-owner model at 2 waves/SIMD. One block = one batch
// = 512 threads = 8 waves. Lane L of a CELL wave owns h-index L of its layer:
// all 4 whh gate rows in registers -> gates never leave the lane, scalar cell
// state, no exchange. All slack-tolerant ih rows live in PRODUCER waves:
//   W0/W1/W2: cell waves, layers 0/1/2 (4 whh rows = 128 fdot2 + cell)
//   W3: wih1_o | W4: wih1_i | W5: wih1_f | W6: wih1_g  (32 fdot2 each, h0)
//   W7: wih2_{i,f,g,o} (128 fdot2, h1)
// HW wave->SIMD round robin (wv%4) pairs each cell wave with a light
// producer: every SIMD carries exactly 160 fdot2/iter, and the partner's dot
// stream fills the cell wave's gather/act/barrier stalls (the 48% idle at
// R10's 1 wave/SIMD). ONE barrier/iter: p-buffers and cross-layer h all have
// 1-step slack; whh gates are in-lane. Schedule (R10): cell_l computes
// h_l[s-2l]; producers compute p from rd-slot rings.
// launch_bounds(512,2): VGPR cap 256 >= ~196 needed -> weights stay
// architectural (the R2-R9 AGPR-read tax stays dead).
__global__ __launch_bounds__(512, 2) void lstm3_fused(
    const float* __restrict__ x,
    const float* __restrict__ Wih0, const float* __restrict__ Whh0,
    const float* __restrict__ bih0, const float* __restrict__ bhh0,
    const float* __restrict__ Wih1, const float* __restrict__ Whh1,
    const float* __restrict__ bih1, const float* __restrict__ bhh1,
    const float* __restrict__ Wih2, const float* __restrict__ Whh2,
    const float* __restrict__ bih2, const float* __restrict__ bhh2,
    const float* __restrict__ fcW,  const float* __restrict__ fcb,
    float* __restrict__ out)
{
    const int b   = blockIdx.x;
    const int tid = threadIdx.x;
    const int wv  = tid >> 6;         // 0..7 (wave-uniform)
    const int L   = tid & 63;         // owned h-index / row-lane

    __shared__ __align__(16) _Float16 h0f[2][HID];
    __shared__ __align__(16) _Float16 h1f[2][HID];
    __shared__ __align__(16) _Float16 h2f[2][HID];
    __shared__ float p1buf[2][4 * HID], p2buf[2][4 * HID];
    __shared__ __align__(16) float xs[NITER];   // 2052 floats = 513 float4

    // Stage x[b,0,:] (512 float4 by 512 threads) + zero pad + zero rings.
    {
        const float4* xg4 = reinterpret_cast<const float4*>(x + b * T_LEN);
        float4* xs4 = reinterpret_cast<float4*>(xs);
        xs4[tid] = xg4[tid];
        if (tid == 0) xs4[512] = make_float4(0.f, 0.f, 0.f, 0.f);
    }
    if (tid < HID) {
        h0f[0][tid] = (_Float16)0.f; h0f[1][tid] = (_Float16)0.f;
        h1f[0][tid] = (_Float16)0.f; h1f[1][tid] = (_Float16)0.f;
        h2f[0][tid] = (_Float16)0.f; h2f[1][tid] = (_Float16)0.f;
    }

    const float sSig = -LOG2E, sTan = -2.f * LOG2E;

    uint4v w[4][8];                   // cell: 4 whh rows; W7: 4 wih2 rows;
                                      // W3-6: only w[0] used (1 wih1 row)
    float bias[4] = {0.f, 0.f, 0.f, 0.f};
    float wx[4]   = {0.f, 0.f, 0.f, 0.f};
    int   pofs    = 0;                // producer p-slot offset (W3-6)

    if (wv < 3) {
        const float* Wh = (wv == 0) ? Whh0 : (wv == 1) ? Whh1 : Whh2;
        const float* bi = (wv == 0) ? bih0 : (wv == 1) ? bih1 : bih2;
        const float* bh = (wv == 0) ? bhh0 : (wv == 1) ? bhh1 : bhh2;
        const float scl[4] = {sSig, sSig, sTan, sSig};
        #pragma unroll
        for (int k = 0; k < 4; ++k) {
            cvt_row(Wh, k * 64 + L, scl[k], w[k]);
            bias[k] = (bi[k * 64 + L] + bh[k * 64 + L]) * scl[k];
        }
        if (wv == 0) {
            #pragma unroll
            for (int k = 0; k < 4; ++k) wx[k] = Wih0[k * 64 + L] * scl[k];
        }
    } else if (wv < 7) {
        // One wih1 row: W3 -> o(set 3), W4 -> i(0), W5 -> f(1), W6 -> g(2).
        const int set = (wv == 3) ? 3 : (wv - 4);
        cvt_row(Wih1, set * 64 + L, (set == 2) ? sTan : sSig, w[0]);
        pofs = set * 64 + L;
    } else {
        #pragma unroll
        for (int k = 0; k < 4; ++k)
            cvt_row(Wih2, k * 64 + L, (k == 2) ? sTan : sSig, w[k]);
    }

    // Hoisted ring bases.
    _Float16* selfRing = (wv == 0) ? h0f[0] : (wv == 1) ? h1f[0] : h2f[0];
    const float* pin   = (wv == 1) ? p1buf[0] : p2buf[0];   // cell1/2 gate input
    const int soff = 2 * wv;          // cell window offset

    float c = 0.f;
    __syncthreads();

    for (int s = 0; s < NITER; ++s) {
        const int rd = (s + 1) & 1;
        const int wr = s & 1;

        if (wv >= 7) {
            // Producer W7: all 4 wih2 rows vs h1[rd].
            uint4v A[8];
            gather8(reinterpret_cast<const uint4v*>(h1f[rd]), A);
            p2buf[wr][L]       = dot32(w[0], A, 0.f);
            p2buf[wr][64 + L]  = dot32(w[1], A, 0.f);
            p2buf[wr][128 + L] = dot32(w[2], A, 0.f);
            p2buf[wr][192 + L] = dot32(w[3], A, 0.f);
        } else if (wv >= 3) {
            // Producers W3-6: one wih1 row vs h0[rd].
            uint4v A[8];
            gather8(reinterpret_cast<const uint4v*>(h0f[rd]), A);
            p1buf[wr][pofs] = dot32(w[0], A, 0.f);
        } else {
            // Cell wave: gather own ring, 4 in-lane gate dots, local cell.
            uint4v A[8];
            gather8(reinterpret_cast<const uint4v*>(selfRing + rd * HID), A);

            float d0, d1, d2, d3;
            if (wv == 0) {
                float xv = xs[s];
                d0 = fmaf(wx[0], xv, bias[0]); d1 = fmaf(wx[1], xv, bias[1]);
                d2 = fmaf(wx[2], xv, bias[2]); d3 = fmaf(wx[3], xv, bias[3]);
            } else {
                const float* pb = pin + rd * 4 * HID;
                d0 = bias[0] + pb[L];       d1 = bias[1] + pb[64 + L];
                d2 = bias[2] + pb[128 + L]; d3 = bias[3] + pb[192 + L];
            }

            d0 = dot32(w[0], A, d0);
            d1 = dot32(w[1], A, d1);
            d2 = dot32(w[2], A, d2);
            d3 = dot32(w[3], A, d3);

            float ai = RCPF(1.f + EXP2F(d0));
            float af = RCPF(1.f + EXP2F(d1));
            float ag = fmaf(2.f, RCPF(1.f + EXP2F(d2)), -1.f);
            float ao = RCPF(1.f + EXP2F(d3));

            if ((unsigned)(s - soff) < (unsigned)T_LEN) {
                c = fmaf(af, c, ai * ag);
                float tc = fmaf(2.f, RCPF(1.f + EXP2F(-2.f * LOG2E * c)), -1.f);
                float h  = ao * tc;
                selfRing[wr * HID + L] = (_Float16)h;
            }
        }
        __syncthreads();   // p-buffers + cross-layer h: 1-step slack edges
    }

    // Final FC (f32): h2[T-1] written at s=2051 (odd) -> slot 1.
    if (tid < EMB) {
        float acc = fcb[tid];
        const _Float16* hf = h2f[1];
        const float4* W4 = reinterpret_cast<const float4*>(fcW + tid * HID);
        #pragma unroll
        for (int k = 0; k < 16; ++k) {
            float4 wv4 = W4[k];
            acc = fmaf(wv4.x, (float)hf[4 * k + 0], acc);
            acc = fmaf(wv4.y, (float)hf[4 * k + 1], acc);
            acc = fmaf(wv4.z, (float)hf[4 * k + 2], acc);
            acc = fmaf(wv4.w, (float)hf[4 * k + 3], acc);
        }
        out[b * EMB + tid] = acc;
    }
}

extern "C" void kernel_launch(void* const* d_in, const int* in_sizes, int n_in,
                              void* d_out, int out_size, void* d_ws, size_t ws_size,
                              hipStream_t stream) {
    const float* x    = (const float*)d_in[0];
    const float* Wih0 = (const float*)d_in[1];
    const float* Whh0 = (const float*)d_in[2];
    const float* bih0 = (const float*)d_in[3];
    const float* bhh0 = (const float*)d_in[4];
    const float* Wih1 = (const float*)d_in[5];
    const float* Whh1 = (const float*)d_in[6];
    const float* bih1 = (const float*)d_in[7];
    const float* bhh1 = (const float*)d_in[8];
    const float* Wih2 = (const float*)d_in[9];
    const float* Whh2 = (const float*)d_in[10];
    const float* bih2 = (const float*)d_in[11];
    const float* bhh2 = (const float*)d_in[12];
    const float* fcW  = (const float*)d_in[13];
    const float* fcb  = (const float*)d_in[14];
    float* out = (float*)d_out;

    lstm3_fused<<<dim3(256), dim3(512), 0, stream>>>(
        x, Wih0, Whh0, bih0, bhh0,
        Wih1, Whh1, bih1, bhh1,
        Wih2, Whh2, bih2, bhh2,
        fcW, fcb, out);
}